// Round 3
// baseline (1025.850 us; speedup 1.0000x reference)
//
#include <hip/hip_runtime.h>
#include <hip/hip_bf16.h>

#define NPTS 262144
#define ROWS 64           // rows per block
#define SA 320            // bufA row stride (elems) = 640 B (multiple of 128 B)
#define SB 256            // bufB row stride (elems) = 512 B (multiple of 128 B)
#define LDS_BYTES ((ROWS*SA + ROWS*SB)*2)   // 73728 B -> 2 blocks/CU

typedef __attribute__((ext_vector_type(8))) short short8;
typedef __attribute__((ext_vector_type(4))) float f32x4;

__device__ __forceinline__ ushort bfu(float f) {
  union { float f; unsigned u; } x; x.f = f;
  unsigned r = x.u + 0x7fffu + ((x.u >> 16) & 1u);
  return (ushort)(r >> 16);
}

// pack two floats -> two bf16 in one u32 (v_cvt_pk_bf16_f32)
__device__ __forceinline__ unsigned pk2(float a, float b) {
  __hip_bfloat162 h = __float22bfloat162_rn(float2{a, b});
  return *reinterpret_cast<unsigned*>(&h);
}

// XOR-swizzle: flip byte-address bits 4..6 with (row&7). Row strides are
// multiples of 128B so row base contributes 0 to bits 0..6 -> bijective per row,
// 16B-aligned reads stay 16B-contiguous. Reads: each 8-lane group covers 8
// distinct 16B bank slots -> conflict-free. Writes (b64): 2-way (free).
__device__ __forceinline__ uintptr_t swz(uintptr_t a, int row) {
  return a ^ (uintptr_t)((row & 7) << 4);
}

// ---------------- prep: pack weights to fragment-major bf16 ----------------
// dst layout: [(ct*nkt + kt)*64 + lane]*8 + j  ==  W[ct*16 + (lane&15)][kt*32 + (lane>>4)*8 + j]
__global__ void pack_w(const float* __restrict__ w, ushort* __restrict__ dst,
                       int OUT, int KIN, int nct, int nkt) {
  int t = blockIdx.x * 256 + threadIdx.x;
  int total = nct * nkt * 64;
  if (t >= total) return;
  int l  = t & 63;
  int kt = (t >> 6) % nkt;
  int ct = (t >> 6) / nkt;
  int row = ct * 16 + (l & 15);
  int k0  = kt * 32 + (l >> 4) * 8;
  ushort* d = dst + (size_t)t * 8;
  #pragma unroll
  for (int j = 0; j < 8; ++j) {
    int k = k0 + j;
    float v = (row < OUT && k < KIN) ? w[(size_t)row * KIN + k] : 0.f;
    d[j] = bfu(v);
  }
}

__global__ void pack_b(const float* __restrict__ b, float* __restrict__ dst, int OUT, int OUTP) {
  int i = blockIdx.x * 256 + threadIdx.x;
  if (i < OUTP) dst[i] = (i < OUT) ? b[i] : 0.f;
}

// ---------------- generic MFMA layer (swapped operands, swizzled LDS) -------
// Computes D^T = W * Act^T per 16x16 tile: lane holds 4 consecutive OUTPUT
// CHANNELS (lk*4+i) for point row (r*16+lr) -> packed b64 LDS write.
// A (LDS): k-tiles < KSPLIT from a0 (stride s0), >= KSPLIT from a1 (stride s1).
// a0/a1 base col offsets must be multiples of 64 elems (128 B) for the swizzle.
template<int NKT, int KSPLIT, int NC, bool RELU>
__device__ __forceinline__ void layerg(
    const ushort* __restrict__ wpk, const float* __restrict__ bias,
    const ushort* a0, int s0, const ushort* a1, int s1,
    ushort* dst, int sd, int dstCol0,
    int ctBase, int lane)
{
  const int lr = lane & 15, lk = lane >> 4;
  const uintptr_t sx = (uintptr_t)((lr & 7) << 4);   // row&7 == lr&7 (rows = r*16+lr)
  f32x4 acc[4][NC];
  #pragma unroll
  for (int c = 0; c < NC; ++c) {
    f32x4 b4 = *(const f32x4*)(bias + (ctBase + c) * 16 + lk * 4);
    #pragma unroll
    for (int r = 0; r < 4; ++r) acc[r][c] = b4;
  }
  #pragma unroll 4
  for (int kt = 0; kt < NKT; ++kt) {
    short8 av[4];
    if (kt < KSPLIT) {
      int ko = kt * 32 + lk * 8;
      #pragma unroll
      for (int r = 0; r < 4; ++r)
        av[r] = *(const short8*)(((uintptr_t)(a0 + (size_t)(r * 16 + lr) * s0 + ko)) ^ sx);
    } else {
      int ko = (kt - KSPLIT) * 32 + lk * 8;
      #pragma unroll
      for (int r = 0; r < 4; ++r)
        av[r] = *(const short8*)(((uintptr_t)(a1 + (size_t)(r * 16 + lr) * s1 + ko)) ^ sx);
    }
    #pragma unroll
    for (int c = 0; c < NC; ++c) {
      short8 bv = *(const short8*)(wpk + (size_t)(((ctBase + c) * NKT + kt) * 64 + lane) * 8);
      #pragma unroll
      for (int r = 0; r < 4; ++r)
        acc[r][c] = __builtin_amdgcn_mfma_f32_16x16x32_bf16(bv, av[r], acc[r][c], 0, 0, 0);
    }
  }
  #pragma unroll
  for (int c = 0; c < NC; ++c)
    #pragma unroll
    for (int r = 0; r < 4; ++r) {
      float v0 = acc[r][c][0], v1 = acc[r][c][1], v2 = acc[r][c][2], v3 = acc[r][c][3];
      if (RELU) {
        v0 = fmaxf(v0, 0.f); v1 = fmaxf(v1, 0.f);
        v2 = fmaxf(v2, 0.f); v3 = fmaxf(v3, 0.f);
      }
      uint2 p; p.x = pk2(v0, v1); p.y = pk2(v2, v3);
      *(uint2*)(((uintptr_t)(dst + (size_t)(r * 16 + lr) * sd + dstCol0 + (ctBase + c) * 16 + lk * 4)) ^ sx) = p;
    }
}

// ---------------- fused NeRF ----------------
extern __shared__ ushort smem[];

__global__ __launch_bounds__(512, 4) void nerf_fused(
    const float* __restrict__ xyz, const float* __restrict__ dvec,
    const ushort* __restrict__ wp, const float* __restrict__ bp,
    float* __restrict__ out)
{
  ushort* bufA = smem;               // [64][SA]; cols 256..319 hold x_emb
  ushort* bufB = smem + ROWS * SA;   // [64][SB]
  const int tid  = threadIdx.x;
  const int row0 = blockIdx.x * ROWS;
  const int wave = tid >> 6, lane = tid & 63;
  const int lr = lane & 15, lk = lane >> 4;
  const uintptr_t sxl = (uintptr_t)((lr & 7) << 4);

  // posenc(xyz) -> bufA[:,256..319]  (63 cols + zero pad), swizzled scalar writes
  {
    int r = tid >> 3, j = tid & 7;
    const float* x = xyz + (size_t)(row0 + r) * 3;
    float x0 = x[0], x1 = x[1], x2 = x[2];
    uintptr_t rowp = (uintptr_t)(bufA + (size_t)r * SA + 256);
    int rs = (r & 7) << 4;
    #define STX(c, v) *(ushort*)((rowp + 2*(c)) ^ rs) = (v)
    if (j == 7) { STX(0, bfu(x0)); STX(1, bfu(x1)); STX(2, bfu(x2)); STX(63, 0); }
    for (int l = j; l < 10; l += 8) {
      float f = (float)(1 << l);
      int b = 3 + l * 6;
      STX(b + 0, bfu(__sinf(x0 * f))); STX(b + 1, bfu(__sinf(x1 * f))); STX(b + 2, bfu(__sinf(x2 * f)));
      STX(b + 3, bfu(__cosf(x0 * f))); STX(b + 4, bfu(__cosf(x1 * f))); STX(b + 5, bfu(__cosf(x2 * f)));
    }
    #undef STX
  }
  __syncthreads();
  layerg<2, 2, 2, true >(wp + 0,      bp + 0,    bufA + 256, SA, bufA, SA, bufB, SB, 0, wave * 2, lane);
  __syncthreads();
  layerg<8, 8, 2, true >(wp + 16384,  bp + 256,  bufB, SB, bufB, SB, bufA, SA, 0, wave * 2, lane);
  __syncthreads();
  layerg<8, 8, 2, true >(wp + 81920,  bp + 512,  bufA, SA, bufA, SA, bufB, SB, 0, wave * 2, lane);
  __syncthreads();
  layerg<8, 8, 2, true >(wp + 147456, bp + 768,  bufB, SB, bufB, SB, bufA, SA, 0, wave * 2, lane);
  __syncthreads();
  layerg<8, 8, 2, true >(wp + 212992, bp + 1024, bufA, SA, bufA, SA, bufB, SB, 0, wave * 2, lane);
  __syncthreads();
  // L2_0: K = 256 (h in bufB) + 64 (x_emb in bufA cols 256..)
  layerg<10, 8, 2, true>(wp + 278528, bp + 1280, bufB, SB, bufA + 256, SA, bufA, SA, 0, wave * 2, lane);
  __syncthreads();
  layerg<8, 8, 2, true >(wp + 360448, bp + 1536, bufA, SA, bufA, SA, bufB, SB, 0, wave * 2, lane);
  __syncthreads();
  layerg<8, 8, 2, true >(wp + 425984, bp + 1792, bufB, SB, bufB, SB, bufA, SA, 0, wave * 2, lane);
  __syncthreads();
  // L2_3: h (no relu) -> bufB[:,0..255]; sigma (ct 16, col 256) -> out (relu)
  layerg<8, 8, 2, false>(wp + 491520, bp + 2048, bufA, SA, bufA, SA, bufB, SB, 0, wave * 2, lane);
  if (wave == 0) {
    const ushort* w23 = wp + 491520;
    float bb = bp[2048 + 256 + lr];
    f32x4 acc2[4];
    #pragma unroll
    for (int r = 0; r < 4; ++r) acc2[r] = (f32x4){bb, bb, bb, bb};
    #pragma unroll 2
    for (int kt = 0; kt < 8; ++kt) {
      short8 bv = *(const short8*)(w23 + (size_t)((16 * 8 + kt) * 64 + lane) * 8);
      #pragma unroll
      for (int r = 0; r < 4; ++r) {
        short8 av = *(const short8*)(((uintptr_t)(bufA + (size_t)(r * 16 + lr) * SA + kt * 32 + lk * 8)) ^ sxl);
        acc2[r] = __builtin_amdgcn_mfma_f32_16x16x32_bf16(av, bv, acc2[r], 0, 0, 0);
      }
    }
    if (lr == 0) {
      #pragma unroll
      for (int r = 0; r < 4; ++r)
        #pragma unroll
        for (int i = 0; i < 4; ++i)
          out[(size_t)3 * NPTS + row0 + r * 16 + lk * 4 + i] = fmaxf(acc2[r][i], 0.f);
    }
  }
  __syncthreads();
  // d_emb -> bufA[:,0..31] (27 cols + zero pad)
  {
    int r = tid >> 3, j = tid & 7;
    const float* x = dvec + (size_t)(row0 + r) * 3;
    float x0 = x[0], x1 = x[1], x2 = x[2];
    uintptr_t rowp = (uintptr_t)(bufA + (size_t)r * SA);
    int rs = (r & 7) << 4;
    #define STX(c, v) *(ushort*)((rowp + 2*(c)) ^ rs) = (v)
    if (j == 7) {
      STX(0, bfu(x0)); STX(1, bfu(x1)); STX(2, bfu(x2));
      #pragma unroll
      for (int q = 27; q < 32; ++q) STX(q, 0);
    }
    if (j < 4) {
      float f = (float)(1 << j);
      int b = 3 + j * 6;
      STX(b + 0, bfu(__sinf(x0 * f))); STX(b + 1, bfu(__sinf(x1 * f))); STX(b + 2, bfu(__sinf(x2 * f)));
      STX(b + 3, bfu(__cosf(x0 * f))); STX(b + 4, bfu(__cosf(x1 * f))); STX(b + 5, bfu(__cosf(x2 * f)));
    }
    #undef STX
  }
  __syncthreads();
  // LR0: K = 256 (h in bufB) + 32 (d_emb in bufA cols 0..31); out 128 -> bufA cols 128..255
  layerg<9, 8, 1, true>(wp + 561152, bp + 2320, bufB, SB, bufA, SA, bufA, SA, 128, wave, lane);
  __syncthreads();
  // LR1: K = 128 (g in bufA cols 128..255), out 3 of 16 -> sigmoid -> out
  if (wave < 4) {
    const ushort* w = wp + 598016;
    float bb = bp[2448 + lr];
    f32x4 acc = (f32x4){bb, bb, bb, bb};
    #pragma unroll
    for (int kt = 0; kt < 4; ++kt) {
      short8 av = *(const short8*)(((uintptr_t)(bufA + (size_t)(wave * 16 + lr) * SA + 128 + kt * 32 + lk * 8)) ^ sxl);
      short8 bv = *(const short8*)(w + (size_t)(kt * 64 + lane) * 8);
      acc = __builtin_amdgcn_mfma_f32_16x16x32_bf16(av, bv, acc, 0, 0, 0);
    }
    if (lr < 3) {
      #pragma unroll
      for (int i = 0; i < 4; ++i) {
        int grow = row0 + wave * 16 + lk * 4 + i;
        out[(size_t)grow * 3 + lr] = 1.f / (1.f + __expf(-acc[i]));
      }
    }
  }
}

// ---------------- host ----------------
extern "C" void kernel_launch(void* const* d_in, const int* in_sizes, int n_in,
                              void* d_out, int out_size, void* d_ws, size_t ws_size,
                              hipStream_t stream) {
  const float* xyz  = (const float*)d_in[0];
  const float* dvec = (const float*)d_in[1];
  ushort* wp = (ushort*)d_ws;
  float*  bp = (float*)((char*)d_ws + 1200128);

  struct WSpec { int idx, OUT, KIN, nct, nkt, off; };
  const WSpec wspecs[11] = {
    { 2, 256,  63, 16,  2,      0},
    { 4, 256, 256, 16,  8,  16384},
    { 6, 256, 256, 16,  8,  81920},
    { 8, 256, 256, 16,  8, 147456},
    {10, 256, 256, 16,  8, 212992},
    {12, 256, 319, 16, 10, 278528},
    {14, 256, 256, 16,  8, 360448},
    {16, 256, 256, 16,  8, 425984},
    {18, 257, 256, 17,  8, 491520},
    {20, 128, 283,  8,  9, 561152},
    {22,   3, 128,  1,  4, 598016},
  };
  for (int i = 0; i < 11; ++i) {
    int total = wspecs[i].nct * wspecs[i].nkt * 64;
    pack_w<<<dim3((total + 255) / 256), dim3(256), 0, stream>>>(
      (const float*)d_in[wspecs[i].idx], wp + wspecs[i].off,
      wspecs[i].OUT, wspecs[i].KIN, wspecs[i].nct, wspecs[i].nkt);
  }
  struct BSpec { int idx, OUT, OUTP, off; };
  const BSpec bspecs[11] = {
    { 3, 256, 256,    0}, { 5, 256, 256,  256}, { 7, 256, 256,  512}, { 9, 256, 256,  768},
    {11, 256, 256, 1024}, {13, 256, 256, 1280}, {15, 256, 256, 1536}, {17, 256, 256, 1792},
    {19, 257, 272, 2048}, {21, 128, 128, 2320}, {23,   3,  16, 2448},
  };
  for (int i = 0; i < 11; ++i) {
    pack_b<<<dim3((bspecs[i].OUTP + 255) / 256), dim3(256), 0, stream>>>(
      (const float*)d_in[bspecs[i].idx], bp + bspecs[i].off, bspecs[i].OUT, bspecs[i].OUTP);
  }

  hipFuncSetAttribute(reinterpret_cast<const void*>(nerf_fused),
                      hipFuncAttributeMaxDynamicSharedMemorySize, LDS_BYTES);
  nerf_fused<<<dim3(NPTS / ROWS), dim3(512), LDS_BYTES, stream>>>(xyz, dvec, wp, bp, (float*)d_out);
}

// Round 4
// 651.255 us; speedup vs baseline: 1.5752x; 1.5752x over previous
//
#include <hip/hip_runtime.h>
#include <hip/hip_bf16.h>

#define NPTS 262144
#define ROWS 64           // rows per block
#define SA 320            // bufA row stride (elems) = 640 B (multiple of 128 B)
#define SB 256            // bufB row stride (elems) = 512 B (multiple of 128 B)
#define LDS_BYTES ((ROWS*SA + ROWS*SB)*2)   // 73728 B -> 2 blocks/CU

typedef __attribute__((ext_vector_type(8))) short short8;
typedef __attribute__((ext_vector_type(4))) float f32x4;

__device__ __forceinline__ ushort bfu(float f) {
  union { float f; unsigned u; } x; x.f = f;
  unsigned r = x.u + 0x7fffu + ((x.u >> 16) & 1u);
  return (ushort)(r >> 16);
}

// pack two floats -> two bf16 in one u32 (v_cvt_pk_bf16_f32)
__device__ __forceinline__ unsigned pk2(float a, float b) {
  __hip_bfloat162 h = __float22bfloat162_rn(float2{a, b});
  return *reinterpret_cast<unsigned*>(&h);
}

// ---------------- prep: pack weights to fragment-major bf16 ----------------
// dst layout: [(ct*nkt + kt)*64 + lane]*8 + j  ==  W[ct*16 + (lane&15)][kt*32 + (lane>>4)*8 + j]
__global__ void pack_w(const float* __restrict__ w, ushort* __restrict__ dst,
                       int OUT, int KIN, int nct, int nkt) {
  int t = blockIdx.x * 256 + threadIdx.x;
  int total = nct * nkt * 64;
  if (t >= total) return;
  int l  = t & 63;
  int kt = (t >> 6) % nkt;
  int ct = (t >> 6) / nkt;
  int row = ct * 16 + (l & 15);
  int k0  = kt * 32 + (l >> 4) * 8;
  ushort* d = dst + (size_t)t * 8;
  #pragma unroll
  for (int j = 0; j < 8; ++j) {
    int k = k0 + j;
    float v = (row < OUT && k < KIN) ? w[(size_t)row * KIN + k] : 0.f;
    d[j] = bfu(v);
  }
}

__global__ void pack_b(const float* __restrict__ b, float* __restrict__ dst, int OUT, int OUTP) {
  int i = blockIdx.x * 256 + threadIdx.x;
  if (i < OUTP) dst[i] = (i < OUT) ? b[i] : 0.f;
}

// ---------------- generic MFMA layer (swapped operands, swizzled LDS) -------
// Swizzle: element-index XOR with (row&7)<<3  == byte bits 4..6. Row strides
// and col bases are multiples of 64 elems -> bijective within each 64-elem
// line; applied identically on write and read. Index XOR keeps addrspace(3)
// inference (DS ops, 32-bit addresses) — NEVER flatten the pointer.
// Computes D^T = W * Act^T per 16x16 tile: lane holds 4 consecutive OUTPUT
// CHANNELS (lk*4+i) for point row (r*16+lr) -> packed b64 LDS write.
template<int NKT, int KSPLIT, int NC, bool RELU>
__device__ __forceinline__ void layerg(
    const ushort* __restrict__ wpk, const float* __restrict__ bias,
    const ushort* a0, int s0, const ushort* a1, int s1,
    ushort* dst, int sd, int dstCol0,
    int ctBase, int lane)
{
  const int lr = lane & 15, lk = lane >> 4;
  const int sxe = (lr & 7) << 3;     // row&7 == lr&7 (rows = r*16+lr)
  f32x4 acc[4][NC];
  #pragma unroll
  for (int c = 0; c < NC; ++c) {
    f32x4 b4 = *(const f32x4*)(bias + (ctBase + c) * 16 + lk * 4);
    #pragma unroll
    for (int r = 0; r < 4; ++r) acc[r][c] = b4;
  }
  #pragma unroll 4
  for (int kt = 0; kt < NKT; ++kt) {
    short8 av[4];
    if (kt < KSPLIT) {
      int ko = kt * 32 + lk * 8;
      #pragma unroll
      for (int r = 0; r < 4; ++r)
        av[r] = *(const short8*)(a0 + (((r * 16 + lr) * s0 + ko) ^ sxe));
    } else {
      int ko = (kt - KSPLIT) * 32 + lk * 8;
      #pragma unroll
      for (int r = 0; r < 4; ++r)
        av[r] = *(const short8*)(a1 + (((r * 16 + lr) * s1 + ko) ^ sxe));
    }
    #pragma unroll
    for (int c = 0; c < NC; ++c) {
      short8 bv = *(const short8*)(wpk + (size_t)(((ctBase + c) * NKT + kt) * 64 + lane) * 8);
      #pragma unroll
      for (int r = 0; r < 4; ++r)
        acc[r][c] = __builtin_amdgcn_mfma_f32_16x16x32_bf16(bv, av[r], acc[r][c], 0, 0, 0);
    }
  }
  #pragma unroll
  for (int c = 0; c < NC; ++c)
    #pragma unroll
    for (int r = 0; r < 4; ++r) {
      float v0 = acc[r][c][0], v1 = acc[r][c][1], v2 = acc[r][c][2], v3 = acc[r][c][3];
      if (RELU) {
        v0 = fmaxf(v0, 0.f); v1 = fmaxf(v1, 0.f);
        v2 = fmaxf(v2, 0.f); v3 = fmaxf(v3, 0.f);
      }
      uint2 p; p.x = pk2(v0, v1); p.y = pk2(v2, v3);
      *(uint2*)(dst + ((((r * 16 + lr) * sd + dstCol0 + (ctBase + c) * 16 + lk * 4)) ^ sxe)) = p;
    }
}

// ---------------- fused NeRF ----------------
extern __shared__ ushort smem[];

__global__ __launch_bounds__(512, 4) void nerf_fused(
    const float* __restrict__ xyz, const float* __restrict__ dvec,
    const ushort* __restrict__ wp, const float* __restrict__ bp,
    float* __restrict__ out)
{
  ushort* bufA = smem;               // [64][SA]; cols 256..319 hold x_emb
  ushort* bufB = smem + ROWS * SA;   // [64][SB]
  const int tid  = threadIdx.x;
  const int row0 = blockIdx.x * ROWS;
  const int wave = tid >> 6, lane = tid & 63;
  const int lr = lane & 15, lk = lane >> 4;
  const int sxl = (lr & 7) << 3;

  // posenc(xyz) -> bufA[:,256..319]  (63 cols + zero pad), swizzled scalar writes
  {
    int r = tid >> 3, j = tid & 7;
    const float* x = xyz + (size_t)(row0 + r) * 3;
    float x0 = x[0], x1 = x[1], x2 = x[2];
    ushort* rowp = bufA + (size_t)r * SA + 256;
    int rs = (r & 7) << 3;
    #define STX(c, v) rowp[(c) ^ rs] = (v)
    if (j == 7) { STX(0, bfu(x0)); STX(1, bfu(x1)); STX(2, bfu(x2)); STX(63, 0); }
    for (int l = j; l < 10; l += 8) {
      float f = (float)(1 << l);
      int b = 3 + l * 6;
      STX(b + 0, bfu(__sinf(x0 * f))); STX(b + 1, bfu(__sinf(x1 * f))); STX(b + 2, bfu(__sinf(x2 * f)));
      STX(b + 3, bfu(__cosf(x0 * f))); STX(b + 4, bfu(__cosf(x1 * f))); STX(b + 5, bfu(__cosf(x2 * f)));
    }
    #undef STX
  }
  __syncthreads();
  layerg<2, 2, 2, true >(wp + 0,      bp + 0,    bufA + 256, SA, bufA, SA, bufB, SB, 0, wave * 2, lane);
  __syncthreads();
  layerg<8, 8, 2, true >(wp + 16384,  bp + 256,  bufB, SB, bufB, SB, bufA, SA, 0, wave * 2, lane);
  __syncthreads();
  layerg<8, 8, 2, true >(wp + 81920,  bp + 512,  bufA, SA, bufA, SA, bufB, SB, 0, wave * 2, lane);
  __syncthreads();
  layerg<8, 8, 2, true >(wp + 147456, bp + 768,  bufB, SB, bufB, SB, bufA, SA, 0, wave * 2, lane);
  __syncthreads();
  layerg<8, 8, 2, true >(wp + 212992, bp + 1024, bufA, SA, bufA, SA, bufB, SB, 0, wave * 2, lane);
  __syncthreads();
  // L2_0: K = 256 (h in bufB) + 64 (x_emb in bufA cols 256..)
  layerg<10, 8, 2, true>(wp + 278528, bp + 1280, bufB, SB, bufA + 256, SA, bufA, SA, 0, wave * 2, lane);
  __syncthreads();
  layerg<8, 8, 2, true >(wp + 360448, bp + 1536, bufA, SA, bufA, SA, bufB, SB, 0, wave * 2, lane);
  __syncthreads();
  layerg<8, 8, 2, true >(wp + 425984, bp + 1792, bufB, SB, bufB, SB, bufA, SA, 0, wave * 2, lane);
  __syncthreads();
  // L2_3: h (no relu) -> bufB[:,0..255]; sigma (ct 16, col 256) -> out (relu)
  layerg<8, 8, 2, false>(wp + 491520, bp + 2048, bufA, SA, bufA, SA, bufB, SB, 0, wave * 2, lane);
  if (wave == 0) {
    const ushort* w23 = wp + 491520;
    float bb = bp[2048 + 256 + lr];
    f32x4 acc2[4];
    #pragma unroll
    for (int r = 0; r < 4; ++r) acc2[r] = (f32x4){bb, bb, bb, bb};
    #pragma unroll 2
    for (int kt = 0; kt < 8; ++kt) {
      short8 bv = *(const short8*)(w23 + (size_t)((16 * 8 + kt) * 64 + lane) * 8);
      #pragma unroll
      for (int r = 0; r < 4; ++r) {
        short8 av = *(const short8*)(bufA + ((((r * 16 + lr) * SA + kt * 32 + lk * 8)) ^ sxl));
        acc2[r] = __builtin_amdgcn_mfma_f32_16x16x32_bf16(av, bv, acc2[r], 0, 0, 0);
      }
    }
    if (lr == 0) {
      #pragma unroll
      for (int r = 0; r < 4; ++r)
        #pragma unroll
        for (int i = 0; i < 4; ++i)
          out[(size_t)3 * NPTS + row0 + r * 16 + lk * 4 + i] = fmaxf(acc2[r][i], 0.f);
    }
  }
  __syncthreads();
  // d_emb -> bufA[:,0..31] (27 cols + zero pad; XOR may scatter into cols 0..63,
  // which are dead at this point — read side applies the same XOR)
  {
    int r = tid >> 3, j = tid & 7;
    const float* x = dvec + (size_t)(row0 + r) * 3;
    float x0 = x[0], x1 = x[1], x2 = x[2];
    ushort* rowp = bufA + (size_t)r * SA;
    int rs = (r & 7) << 3;
    #define STX(c, v) rowp[(c) ^ rs] = (v)
    if (j == 7) {
      STX(0, bfu(x0)); STX(1, bfu(x1)); STX(2, bfu(x2));
      #pragma unroll
      for (int q = 27; q < 32; ++q) STX(q, 0);
    }
    if (j < 4) {
      float f = (float)(1 << j);
      int b = 3 + j * 6;
      STX(b + 0, bfu(__sinf(x0 * f))); STX(b + 1, bfu(__sinf(x1 * f))); STX(b + 2, bfu(__sinf(x2 * f)));
      STX(b + 3, bfu(__cosf(x0 * f))); STX(b + 4, bfu(__cosf(x1 * f))); STX(b + 5, bfu(__cosf(x2 * f)));
    }
    #undef STX
  }
  __syncthreads();
  // LR0: K = 256 (h in bufB) + 32 (d_emb in bufA cols 0..31); out 128 -> bufA cols 128..255
  layerg<9, 8, 1, true>(wp + 561152, bp + 2320, bufB, SB, bufA, SA, bufA, SA, 128, wave, lane);
  __syncthreads();
  // LR1: K = 128 (g in bufA cols 128..255), out 3 of 16 -> sigmoid -> out
  if (wave < 4) {
    const ushort* w = wp + 598016;
    float bb = bp[2448 + lr];
    f32x4 acc = (f32x4){bb, bb, bb, bb};
    #pragma unroll
    for (int kt = 0; kt < 4; ++kt) {
      short8 av = *(const short8*)(bufA + ((((wave * 16 + lr) * SA + 128 + kt * 32 + lk * 8)) ^ sxl));
      short8 bv = *(const short8*)(w + (size_t)(kt * 64 + lane) * 8);
      acc = __builtin_amdgcn_mfma_f32_16x16x32_bf16(av, bv, acc, 0, 0, 0);
    }
    if (lr < 3) {
      #pragma unroll
      for (int i = 0; i < 4; ++i) {
        int grow = row0 + wave * 16 + lk * 4 + i;
        out[(size_t)grow * 3 + lr] = 1.f / (1.f + __expf(-acc[i]));
      }
    }
  }
}

// ---------------- host ----------------
extern "C" void kernel_launch(void* const* d_in, const int* in_sizes, int n_in,
                              void* d_out, int out_size, void* d_ws, size_t ws_size,
                              hipStream_t stream) {
  const float* xyz  = (const float*)d_in[0];
  const float* dvec = (const float*)d_in[1];
  ushort* wp = (ushort*)d_ws;
  float*  bp = (float*)((char*)d_ws + 1200128);

  struct WSpec { int idx, OUT, KIN, nct, nkt, off; };
  const WSpec wspecs[11] = {
    { 2, 256,  63, 16,  2,      0},
    { 4, 256, 256, 16,  8,  16384},
    { 6, 256, 256, 16,  8,  81920},
    { 8, 256, 256, 16,  8, 147456},
    {10, 256, 256, 16,  8, 212992},
    {12, 256, 319, 16, 10, 278528},
    {14, 256, 256, 16,  8, 360448},
    {16, 256, 256, 16,  8, 425984},
    {18, 257, 256, 17,  8, 491520},
    {20, 128, 283,  8,  9, 561152},
    {22,   3, 128,  1,  4, 598016},
  };
  for (int i = 0; i < 11; ++i) {
    int total = wspecs[i].nct * wspecs[i].nkt * 64;
    pack_w<<<dim3((total + 255) / 256), dim3(256), 0, stream>>>(
      (const float*)d_in[wspecs[i].idx], wp + wspecs[i].off,
      wspecs[i].OUT, wspecs[i].KIN, wspecs[i].nct, wspecs[i].nkt);
  }
  struct BSpec { int idx, OUT, OUTP, off; };
  const BSpec bspecs[11] = {
    { 3, 256, 256,    0}, { 5, 256, 256,  256}, { 7, 256, 256,  512}, { 9, 256, 256,  768},
    {11, 256, 256, 1024}, {13, 256, 256, 1280}, {15, 256, 256, 1536}, {17, 256, 256, 1792},
    {19, 257, 272, 2048}, {21, 128, 128, 2320}, {23,   3,  16, 2448},
  };
  for (int i = 0; i < 11; ++i) {
    pack_b<<<dim3((bspecs[i].OUTP + 255) / 256), dim3(256), 0, stream>>>(
      (const float*)d_in[bspecs[i].idx], bp + bspecs[i].off, bspecs[i].OUT, bspecs[i].OUTP);
  }

  hipFuncSetAttribute(reinterpret_cast<const void*>(nerf_fused),
                      hipFuncAttributeMaxDynamicSharedMemorySize, LDS_BYTES);
  nerf_fused<<<dim3(NPTS / ROWS), dim3(512), LDS_BYTES, stream>>>(xyz, dvec, wp, bp, (float*)d_out);
}

// Round 5
// 386.289 us; speedup vs baseline: 2.6557x; 1.6859x over previous
//
#include <hip/hip_runtime.h>
#include <hip/hip_bf16.h>

#define NPTS 262144
#define ROWS 64           // rows per block
#define SA 328            // bufA row stride (elems): 656 B -> b128 reads ~2-way (free)
#define SB 264            // bufB row stride (elems): 528 B
#define LDS_BYTES ((ROWS*SA + ROWS*SB)*2)   // 75776 B -> 2 blocks/CU

typedef __attribute__((ext_vector_type(8))) short short8;
typedef __attribute__((ext_vector_type(4))) float f32x4;

__device__ __forceinline__ ushort bfu(float f) {
  union { float f; unsigned u; } x; x.f = f;
  unsigned r = x.u + 0x7fffu + ((x.u >> 16) & 1u);
  return (ushort)(r >> 16);
}

// pack two floats -> two bf16 in one u32 (v_cvt_pk_bf16_f32)
__device__ __forceinline__ unsigned pk2(float a, float b) {
  __hip_bfloat162 h = __float22bfloat162_rn(float2{a, b});
  return *reinterpret_cast<unsigned*>(&h);
}

// ---------------- prep: pack weights to fragment-major bf16 ----------------
// dst layout: [(ct*nkt + kt)*64 + lane]*8 + j  ==  W[ct*16 + (lane&15)][kt*32 + (lane>>4)*8 + j]
__global__ void pack_w(const float* __restrict__ w, ushort* __restrict__ dst,
                       int OUT, int KIN, int nct, int nkt) {
  int t = blockIdx.x * 256 + threadIdx.x;
  int total = nct * nkt * 64;
  if (t >= total) return;
  int l  = t & 63;
  int kt = (t >> 6) % nkt;
  int ct = (t >> 6) / nkt;
  int row = ct * 16 + (l & 15);
  int k0  = kt * 32 + (l >> 4) * 8;
  ushort* d = dst + (size_t)t * 8;
  #pragma unroll
  for (int j = 0; j < 8; ++j) {
    int k = k0 + j;
    float v = (row < OUT && k < KIN) ? w[(size_t)row * KIN + k] : 0.f;
    d[j] = bfu(v);
  }
}

__global__ void pack_b(const float* __restrict__ b, float* __restrict__ dst, int OUT, int OUTP) {
  int i = blockIdx.x * 256 + threadIdx.x;
  if (i < OUTP) dst[i] = (i < OUT) ? b[i] : 0.f;
}

// ---------------- generic MFMA layer (swapped operands, bv prefetch ring) ---
// Computes D^T = W * Act^T per 16x16 tile: lane holds 4 consecutive OUTPUT
// CHANNELS (lk*4+i) for point row (r*16+lr) -> packed b64 LDS write.
// A (LDS): k-tiles < KSPLIT from a0 (stride s0), >= KSPLIT from a1 (stride s1).
// bv weight fragments are prefetched PF k-tiles ahead (static ring, full unroll)
// to cover ~300-cycle L2 latency under the ~150-cycle/4-kt MFMA issue rate.
template<int NKT, int KSPLIT, int NC, bool RELU>
__device__ __forceinline__ void layerg(
    const ushort* __restrict__ wpk, const float* __restrict__ bias,
    const ushort* a0, int s0, const ushort* a1, int s1,
    ushort* dst, int sd, int dstCol0,
    int ctBase, int lane)
{
  constexpr int PF = 4;
  const int lr = lane & 15, lk = lane >> 4;
  const ushort* wbase = wpk + lane * 8;

  short8 bvr[NC][PF];
  #pragma unroll
  for (int p = 0; p < PF; ++p) {
    if (p < NKT) {
      #pragma unroll
      for (int c = 0; c < NC; ++c)
        bvr[c][p] = *(const short8*)(wbase + ((ctBase + c) * NKT + p) * 512);
    }
  }

  f32x4 acc[4][NC];
  #pragma unroll
  for (int c = 0; c < NC; ++c) {
    f32x4 b4 = *(const f32x4*)(bias + (ctBase + c) * 16 + lk * 4);
    #pragma unroll
    for (int r = 0; r < 4; ++r) acc[r][c] = b4;
  }

  #pragma unroll
  for (int kt = 0; kt < NKT; ++kt) {
    // consume ring slot, then refill it early (issue before MFMAs)
    short8 bvu[NC];
    #pragma unroll
    for (int c = 0; c < NC; ++c) bvu[c] = bvr[c][kt % PF];
    if (kt + PF < NKT) {
      #pragma unroll
      for (int c = 0; c < NC; ++c)
        bvr[c][kt % PF] = *(const short8*)(wbase + ((ctBase + c) * NKT + kt + PF) * 512);
    }
    short8 av[4];
    if (kt < KSPLIT) {
      int ko = kt * 32 + lk * 8;
      #pragma unroll
      for (int r = 0; r < 4; ++r)
        av[r] = *(const short8*)(a0 + (r * 16 + lr) * s0 + ko);
    } else {
      int ko = (kt - KSPLIT) * 32 + lk * 8;
      #pragma unroll
      for (int r = 0; r < 4; ++r)
        av[r] = *(const short8*)(a1 + (r * 16 + lr) * s1 + ko);
    }
    __builtin_amdgcn_s_setprio(1);
    #pragma unroll
    for (int c = 0; c < NC; ++c)
      #pragma unroll
      for (int r = 0; r < 4; ++r)
        acc[r][c] = __builtin_amdgcn_mfma_f32_16x16x32_bf16(bvu[c], av[r], acc[r][c], 0, 0, 0);
    __builtin_amdgcn_s_setprio(0);
  }

  #pragma unroll
  for (int c = 0; c < NC; ++c)
    #pragma unroll
    for (int r = 0; r < 4; ++r) {
      float v0 = acc[r][c][0], v1 = acc[r][c][1], v2 = acc[r][c][2], v3 = acc[r][c][3];
      if (RELU) {
        v0 = fmaxf(v0, 0.f); v1 = fmaxf(v1, 0.f);
        v2 = fmaxf(v2, 0.f); v3 = fmaxf(v3, 0.f);
      }
      uint2 p; p.x = pk2(v0, v1); p.y = pk2(v2, v3);
      *(uint2*)(dst + (r * 16 + lr) * sd + dstCol0 + (ctBase + c) * 16 + lk * 4) = p;
    }
}

// ---------------- fused NeRF ----------------
extern __shared__ ushort smem[];

__global__ __launch_bounds__(512, 4) void nerf_fused(
    const float* __restrict__ xyz, const float* __restrict__ dvec,
    const ushort* __restrict__ wp, const float* __restrict__ bp,
    float* __restrict__ out)
{
  ushort* bufA = smem;               // [64][SA]; cols 256..319 hold x_emb
  ushort* bufB = smem + ROWS * SA;   // [64][SB]
  const int tid  = threadIdx.x;
  const int row0 = blockIdx.x * ROWS;
  const int wave = tid >> 6, lane = tid & 63;
  const int lr = lane & 15, lk = lane >> 4;

  // posenc(xyz) -> bufA[:,256..319]  (63 cols + zero pad)
  {
    int r = tid >> 3, j = tid & 7;
    const float* x = xyz + (size_t)(row0 + r) * 3;
    float x0 = x[0], x1 = x[1], x2 = x[2];
    ushort* dst = bufA + r * SA + 256;
    if (j == 7) { dst[0] = bfu(x0); dst[1] = bfu(x1); dst[2] = bfu(x2); dst[63] = 0; }
    for (int l = j; l < 10; l += 8) {
      float f = (float)(1 << l);
      int b = 3 + l * 6;
      dst[b + 0] = bfu(__sinf(x0 * f)); dst[b + 1] = bfu(__sinf(x1 * f)); dst[b + 2] = bfu(__sinf(x2 * f));
      dst[b + 3] = bfu(__cosf(x0 * f)); dst[b + 4] = bfu(__cosf(x1 * f)); dst[b + 5] = bfu(__cosf(x2 * f));
    }
  }
  __syncthreads();
  layerg<2, 2, 2, true >(wp + 0,      bp + 0,    bufA + 256, SA, bufA, SA, bufB, SB, 0, wave * 2, lane);
  __syncthreads();
  layerg<8, 8, 2, true >(wp + 16384,  bp + 256,  bufB, SB, bufB, SB, bufA, SA, 0, wave * 2, lane);
  __syncthreads();
  layerg<8, 8, 2, true >(wp + 81920,  bp + 512,  bufA, SA, bufA, SA, bufB, SB, 0, wave * 2, lane);
  __syncthreads();
  layerg<8, 8, 2, true >(wp + 147456, bp + 768,  bufB, SB, bufB, SB, bufA, SA, 0, wave * 2, lane);
  __syncthreads();
  layerg<8, 8, 2, true >(wp + 212992, bp + 1024, bufA, SA, bufA, SA, bufB, SB, 0, wave * 2, lane);
  __syncthreads();
  // L2_0: K = 256 (h in bufB) + 64 (x_emb in bufA cols 256..)
  layerg<10, 8, 2, true>(wp + 278528, bp + 1280, bufB, SB, bufA + 256, SA, bufA, SA, 0, wave * 2, lane);
  __syncthreads();
  layerg<8, 8, 2, true >(wp + 360448, bp + 1536, bufA, SA, bufA, SA, bufB, SB, 0, wave * 2, lane);
  __syncthreads();
  layerg<8, 8, 2, true >(wp + 425984, bp + 1792, bufB, SB, bufB, SB, bufA, SA, 0, wave * 2, lane);
  __syncthreads();
  // L2_3: h (no relu) -> bufB[:,0..255]; sigma (ct 16, col 256) -> out (relu)
  layerg<8, 8, 2, false>(wp + 491520, bp + 2048, bufA, SA, bufA, SA, bufB, SB, 0, wave * 2, lane);
  if (wave == 0) {
    const ushort* w23 = wp + 491520;
    float bb = bp[2048 + 256 + lr];
    f32x4 acc2[4];
    #pragma unroll
    for (int r = 0; r < 4; ++r) acc2[r] = (f32x4){bb, bb, bb, bb};
    #pragma unroll 2
    for (int kt = 0; kt < 8; ++kt) {
      short8 bv = *(const short8*)(w23 + ((16 * 8 + kt) * 64 + lane) * 8);
      #pragma unroll
      for (int r = 0; r < 4; ++r) {
        short8 av = *(const short8*)(bufA + (r * 16 + lr) * SA + kt * 32 + lk * 8);
        acc2[r] = __builtin_amdgcn_mfma_f32_16x16x32_bf16(av, bv, acc2[r], 0, 0, 0);
      }
    }
    if (lr == 0) {
      #pragma unroll
      for (int r = 0; r < 4; ++r)
        #pragma unroll
        for (int i = 0; i < 4; ++i)
          out[(size_t)3 * NPTS + row0 + r * 16 + lk * 4 + i] = fmaxf(acc2[r][i], 0.f);
    }
  }
  __syncthreads();
  // d_emb -> bufA[:,0..31] (27 cols + zero pad)
  {
    int r = tid >> 3, j = tid & 7;
    const float* x = dvec + (size_t)(row0 + r) * 3;
    float x0 = x[0], x1 = x[1], x2 = x[2];
    ushort* dst = bufA + r * SA;
    if (j == 7) {
      dst[0] = bfu(x0); dst[1] = bfu(x1); dst[2] = bfu(x2);
      #pragma unroll
      for (int q = 27; q < 32; ++q) dst[q] = 0;
    }
    if (j < 4) {
      float f = (float)(1 << j);
      int b = 3 + j * 6;
      dst[b + 0] = bfu(__sinf(x0 * f)); dst[b + 1] = bfu(__sinf(x1 * f)); dst[b + 2] = bfu(__sinf(x2 * f));
      dst[b + 3] = bfu(__cosf(x0 * f)); dst[b + 4] = bfu(__cosf(x1 * f)); dst[b + 5] = bfu(__cosf(x2 * f));
    }
  }
  __syncthreads();
  // LR0: K = 256 (h in bufB) + 32 (d_emb in bufA cols 0..31); out 128 -> bufA cols 128..255
  layerg<9, 8, 1, true>(wp + 561152, bp + 2320, bufB, SB, bufA, SA, bufA, SA, 128, wave, lane);
  __syncthreads();
  // LR1: K = 128 (g in bufA cols 128..255), out 3 of 16 -> sigmoid -> out
  if (wave < 4) {
    const ushort* w = wp + 598016;
    float bb = bp[2448 + lr];
    f32x4 acc = (f32x4){bb, bb, bb, bb};
    #pragma unroll
    for (int kt = 0; kt < 4; ++kt) {
      short8 av = *(const short8*)(bufA + (wave * 16 + lr) * SA + 128 + kt * 32 + lk * 8);
      short8 bv = *(const short8*)(w + (kt * 64 + lane) * 8);
      acc = __builtin_amdgcn_mfma_f32_16x16x32_bf16(av, bv, acc, 0, 0, 0);
    }
    if (lr < 3) {
      #pragma unroll
      for (int i = 0; i < 4; ++i) {
        int grow = row0 + wave * 16 + lk * 4 + i;
        out[(size_t)grow * 3 + lr] = 1.f / (1.f + __expf(-acc[i]));
      }
    }
  }
}

// ---------------- host ----------------
extern "C" void kernel_launch(void* const* d_in, const int* in_sizes, int n_in,
                              void* d_out, int out_size, void* d_ws, size_t ws_size,
                              hipStream_t stream) {
  const float* xyz  = (const float*)d_in[0];
  const float* dvec = (const float*)d_in[1];
  ushort* wp = (ushort*)d_ws;
  float*  bp = (float*)((char*)d_ws + 1200128);

  struct WSpec { int idx, OUT, KIN, nct, nkt, off; };
  const WSpec wspecs[11] = {
    { 2, 256,  63, 16,  2,      0},
    { 4, 256, 256, 16,  8,  16384},
    { 6, 256, 256, 16,  8,  81920},
    { 8, 256, 256, 16,  8, 147456},
    {10, 256, 256, 16,  8, 212992},
    {12, 256, 319, 16, 10, 278528},
    {14, 256, 256, 16,  8, 360448},
    {16, 256, 256, 16,  8, 425984},
    {18, 257, 256, 17,  8, 491520},
    {20, 128, 283,  8,  9, 561152},
    {22,   3, 128,  1,  4, 598016},
  };
  for (int i = 0; i < 11; ++i) {
    int total = wspecs[i].nct * wspecs[i].nkt * 64;
    pack_w<<<dim3((total + 255) / 256), dim3(256), 0, stream>>>(
      (const float*)d_in[wspecs[i].idx], wp + wspecs[i].off,
      wspecs[i].OUT, wspecs[i].KIN, wspecs[i].nct, wspecs[i].nkt);
  }
  struct BSpec { int idx, OUT, OUTP, off; };
  const BSpec bspecs[11] = {
    { 3, 256, 256,    0}, { 5, 256, 256,  256}, { 7, 256, 256,  512}, { 9, 256, 256,  768},
    {11, 256, 256, 1024}, {13, 256, 256, 1280}, {15, 256, 256, 1536}, {17, 256, 256, 1792},
    {19, 257, 272, 2048}, {21, 128, 128, 2320}, {23,   3,  16, 2448},
  };
  for (int i = 0; i < 11; ++i) {
    pack_b<<<dim3((bspecs[i].OUTP + 255) / 256), dim3(256), 0, stream>>>(
      (const float*)d_in[bspecs[i].idx], bp + bspecs[i].off, bspecs[i].OUT, bspecs[i].OUTP);
  }

  hipFuncSetAttribute(reinterpret_cast<const void*>(nerf_fused),
                      hipFuncAttributeMaxDynamicSharedMemorySize, LDS_BYTES);
  nerf_fused<<<dim3(NPTS / ROWS), dim3(512), LDS_BYTES, stream>>>(xyz, dvec, wp, bp, (float*)d_out);
}

// Round 6
// 338.076 us; speedup vs baseline: 3.0344x; 1.1426x over previous
//
#include <hip/hip_runtime.h>
#include <hip/hip_bf16.h>

#define NPTS 262144
#define ROWS 64
#define FR 512                      // elems per fragment line (64 lanes x 8)
// LDS element map: buf0 [4][8][FR] @0, buf1 @16384, xbuf [4][2][FR] @32768 (reused for d_emb [4][1][FR])
#define BUF1_OFF 16384
#define XBUF_OFF 32768
#define LDS_BYTES ((16384*2 + 4096)*2)   // 73728 B -> 2 blocks/CU

typedef __attribute__((ext_vector_type(8))) short short8;
typedef __attribute__((ext_vector_type(4))) float f32x4;

__device__ __forceinline__ ushort bfu(float f) {
  union { float f; unsigned u; } x; x.f = f;
  unsigned r = x.u + 0x7fffu + ((x.u >> 16) & 1u);
  return (ushort)(r >> 16);
}
__device__ __forceinline__ unsigned pk2(float a, float b) {
  __hip_bfloat162 h = __float22bfloat162_rn(float2{a, b});
  return *reinterpret_cast<unsigned*>(&h);
}

// ---------------- prep: pack weights to fragment-major bf16 (UNCHANGED) -----
__global__ void pack_w(const float* __restrict__ w, ushort* __restrict__ dst,
                       int OUT, int KIN, int nct, int nkt) {
  int t = blockIdx.x * 256 + threadIdx.x;
  int total = nct * nkt * 64;
  if (t >= total) return;
  int l  = t & 63;
  int kt = (t >> 6) % nkt;
  int ct = (t >> 6) / nkt;
  int row = ct * 16 + (l & 15);
  int k0  = kt * 32 + (l >> 4) * 8;
  ushort* d = dst + (size_t)t * 8;
  #pragma unroll
  for (int j = 0; j < 8; ++j) {
    int k = k0 + j;
    float v = (row < OUT && k < KIN) ? w[(size_t)row * KIN + k] : 0.f;
    d[j] = bfu(v);
  }
}

__global__ void pack_b(const float* __restrict__ b, float* __restrict__ dst, int OUT, int OUTP) {
  int i = blockIdx.x * 256 + threadIdx.x;
  if (i < OUTP) dst[i] = (i < OUT) ? b[i] : 0.f;
}

// ---------------- generic MFMA layer (fragment-major LDS) -------------------
// Reads av as ready-made B-fragments: a + (r*rs + kt)*FR + lane*8 (contiguous
// 1KB per instr -> conflict-free, offset-foldable). Swapped MFMA: lane holds
// chs ct*16+lk*4+i of point-row lr. Store performs the transpose via lane
// renaming L' = lr + 16*((ct&1)*2 + lk>>1); channel order arrives identity,
// so weight packing is unchanged.
template<int NKT, int KSPLIT, int NC, bool RELU>
__device__ __forceinline__ void layerg(
    const ushort* __restrict__ wpk, const float* __restrict__ bias,
    const ushort* a0, const ushort* a1, int rs1,
    ushort* dst, int ctBase, int lane)
{
  const int lr = lane & 15, lk = lane >> 4;
  f32x4 acc[4][NC];
  #pragma unroll
  for (int c = 0; c < NC; ++c) {
    f32x4 b4 = *(const f32x4*)(bias + (ctBase + c) * 16 + lk * 4);
    #pragma unroll
    for (int r = 0; r < 4; ++r) acc[r][c] = b4;
  }
  #pragma unroll
  for (int kt = 0; kt < NKT; ++kt) {
    short8 av[4];
    #pragma unroll
    for (int r = 0; r < 4; ++r) {
      const ushort* src = (kt < KSPLIT)
        ? (a0 + (r * 8 + kt) * FR + lane * 8)
        : (a1 + (r * rs1 + (kt - KSPLIT)) * FR + lane * 8);
      av[r] = *(const short8*)src;
    }
    #pragma unroll
    for (int c = 0; c < NC; ++c) {
      short8 bv = *(const short8*)(wpk + (size_t)(((ctBase + c) * NKT + kt) * 64 + lane) * 8);
      #pragma unroll
      for (int r = 0; r < 4; ++r)
        acc[r][c] = __builtin_amdgcn_mfma_f32_16x16x32_bf16(bv, av[r], acc[r][c], 0, 0, 0);
    }
  }
  #pragma unroll
  for (int c = 0; c < NC; ++c) {
    const int ct = ctBase + c;
    const int Lp = lr + 16 * ((ct & 1) * 2 + (lk >> 1));
    const int kq = ct >> 1;
    #pragma unroll
    for (int r = 0; r < 4; ++r) {
      float v0 = acc[r][c][0], v1 = acc[r][c][1], v2 = acc[r][c][2], v3 = acc[r][c][3];
      if (RELU) {
        v0 = fmaxf(v0, 0.f); v1 = fmaxf(v1, 0.f);
        v2 = fmaxf(v2, 0.f); v3 = fmaxf(v3, 0.f);
      }
      uint2 p; p.x = pk2(v0, v1); p.y = pk2(v2, v3);
      *(uint2*)(dst + (r * 8 + kq) * FR + Lp * 8 + (lk & 1) * 4) = p;
    }
  }
}

// ---------------- fused NeRF ----------------
extern __shared__ ushort smem[];

__global__ __launch_bounds__(512, 4) void nerf_fused(
    const float* __restrict__ xyz, const float* __restrict__ dvec,
    const ushort* __restrict__ wp, const float* __restrict__ bp,
    float* __restrict__ out)
{
  ushort* buf0 = smem;
  ushort* buf1 = smem + BUF1_OFF;
  ushort* xbuf = smem + XBUF_OFF;
  const int tid  = threadIdx.x;
  const int row0 = blockIdx.x * ROWS;
  const int wave = tid >> 6, lane = tid & 63;
  const int lr = lane & 15, lk = lane >> 4;

  // posenc(xyz) -> x_emb fragments [r][kt2][lane][8]; wave w does (r=w&3, kt=w>>2)
  {
    const int r = wave & 3, kt = wave >> 2;
    const float* x = xyz + (size_t)(row0 + r * 16 + lr) * 3;
    float xv[3] = {x[0], x[1], x[2]};
    const int c0 = kt * 32 + lk * 8;
    unsigned u[4];
    #pragma unroll
    for (int q = 0; q < 4; ++q) {
      ushort h2[2];
      #pragma unroll
      for (int hh = 0; hh < 2; ++hh) {
        int c = c0 + q * 2 + hh;
        float v;
        if (c < 3) v = xv[c];
        else if (c < 63) {
          int idx = c - 3, l = idx / 6, t = idx - l * 6;
          float f = (float)(1 << l);
          float xx = xv[t < 3 ? t : t - 3];
          v = (t < 3) ? __sinf(xx * f) : __cosf(xx * f);
        } else v = 0.f;
        h2[hh] = bfu(v);
      }
      u[q] = (unsigned)h2[0] | ((unsigned)h2[1] << 16);
    }
    uint4* dstv = (uint4*)(xbuf + (r * 2 + kt) * FR + lane * 8);
    *dstv = make_uint4(u[0], u[1], u[2], u[3]);
  }
  __syncthreads();
  layerg<2, 0, 2, true >(wp + 0,      bp + 0,    buf0, xbuf, 2, buf0, wave * 2, lane);
  __syncthreads();
  layerg<8, 8, 2, true >(wp + 16384,  bp + 256,  buf0, xbuf, 2, buf1, wave * 2, lane);
  __syncthreads();
  layerg<8, 8, 2, true >(wp + 81920,  bp + 512,  buf1, xbuf, 2, buf0, wave * 2, lane);
  __syncthreads();
  layerg<8, 8, 2, true >(wp + 147456, bp + 768,  buf0, xbuf, 2, buf1, wave * 2, lane);
  __syncthreads();
  layerg<8, 8, 2, true >(wp + 212992, bp + 1024, buf1, xbuf, 2, buf0, wave * 2, lane);
  __syncthreads();
  // L2_0: K = 256 (h frags in buf0) + 64 (x_emb frags)
  layerg<10, 8, 2, true>(wp + 278528, bp + 1280, buf0, xbuf, 2, buf1, wave * 2, lane);
  __syncthreads();
  // d_emb -> fragments in xbuf [r][1][FR] (x_emb dead now); waves 0..3
  if (wave < 4) {
    const int r = wave;
    const float* d = dvec + (size_t)(row0 + r * 16 + lr) * 3;
    float dv[3] = {d[0], d[1], d[2]};
    const int c0 = lk * 8;
    unsigned u[4];
    #pragma unroll
    for (int q = 0; q < 4; ++q) {
      ushort h2[2];
      #pragma unroll
      for (int hh = 0; hh < 2; ++hh) {
        int c = c0 + q * 2 + hh;
        float v;
        if (c < 3) v = dv[c];
        else if (c < 27) {
          int idx = c - 3, l = idx / 6, t = idx - l * 6;
          float f = (float)(1 << l);
          float xx = dv[t < 3 ? t : t - 3];
          v = (t < 3) ? __sinf(xx * f) : __cosf(xx * f);
        } else v = 0.f;
        h2[hh] = bfu(v);
      }
      u[q] = (unsigned)h2[0] | ((unsigned)h2[1] << 16);
    }
    uint4* dstv = (uint4*)(xbuf + r * FR + lane * 8);
    *dstv = make_uint4(u[0], u[1], u[2], u[3]);
  }
  layerg<8, 8, 2, true >(wp + 360448, bp + 1536, buf1, xbuf, 2, buf0, wave * 2, lane);
  __syncthreads();
  layerg<8, 8, 2, true >(wp + 425984, bp + 1792, buf0, xbuf, 2, buf1, wave * 2, lane);
  __syncthreads();
  // L2_3: h (NO relu) -> buf0 frags; sigma (ct16) by wave 0 from buf1
  layerg<8, 8, 2, false>(wp + 491520, bp + 2048, buf1, xbuf, 2, buf0, wave * 2, lane);
  if (wave == 0) {
    const ushort* w23 = wp + 491520;
    float bb = bp[2048 + 256 + lr];
    f32x4 acc2[4];
    #pragma unroll
    for (int r = 0; r < 4; ++r) acc2[r] = (f32x4){bb, bb, bb, bb};
    #pragma unroll
    for (int kt = 0; kt < 8; ++kt) {
      short8 bv = *(const short8*)(w23 + (size_t)((16 * 8 + kt) * 64 + lane) * 8);
      #pragma unroll
      for (int r = 0; r < 4; ++r) {
        short8 av = *(const short8*)(buf1 + (r * 8 + kt) * FR + lane * 8);
        acc2[r] = __builtin_amdgcn_mfma_f32_16x16x32_bf16(av, bv, acc2[r], 0, 0, 0);
      }
    }
    if (lr == 0) {
      #pragma unroll
      for (int r = 0; r < 4; ++r)
        #pragma unroll
        for (int i = 0; i < 4; ++i)
          out[(size_t)3 * NPTS + row0 + r * 16 + lk * 4 + i] = fmaxf(acc2[r][i], 0.f);
    }
  }
  __syncthreads();
  // LR0: K = 256 (h frags in buf0) + 32 (d_emb frag); out 128 = 8 cts, 1/wave
  layerg<9, 8, 1, true>(wp + 561152, bp + 2320, buf0, xbuf, 1, buf1, wave, lane);
  __syncthreads();
  // LR1: K = 128 (frags kt0..3 in buf1), out 3 of 16 -> sigmoid -> out
  if (wave < 4) {
    const ushort* w = wp + 598016;
    float bb = bp[2448 + lr];
    f32x4 acc = (f32x4){bb, bb, bb, bb};
    #pragma unroll
    for (int kt = 0; kt < 4; ++kt) {
      short8 av = *(const short8*)(buf1 + (wave * 8 + kt) * FR + lane * 8);
      short8 bv = *(const short8*)(w + (size_t)(kt * 64 + lane) * 8);
      acc = __builtin_amdgcn_mfma_f32_16x16x32_bf16(av, bv, acc, 0, 0, 0);
    }
    if (lr < 3) {
      #pragma unroll
      for (int i = 0; i < 4; ++i) {
        int grow = row0 + wave * 16 + lk * 4 + i;
        out[(size_t)grow * 3 + lr] = 1.f / (1.f + __expf(-acc[i]));
      }
    }
  }
}

// ---------------- host ----------------
extern "C" void kernel_launch(void* const* d_in, const int* in_sizes, int n_in,
                              void* d_out, int out_size, void* d_ws, size_t ws_size,
                              hipStream_t stream) {
  const float* xyz  = (const float*)d_in[0];
  const float* dvec = (const float*)d_in[1];
  ushort* wp = (ushort*)d_ws;
  float*  bp = (float*)((char*)d_ws + 1200128);

  struct WSpec { int idx, OUT, KIN, nct, nkt, off; };
  const WSpec wspecs[11] = {
    { 2, 256,  63, 16,  2,      0},
    { 4, 256, 256, 16,  8,  16384},
    { 6, 256, 256, 16,  8,  81920},
    { 8, 256, 256, 16,  8, 147456},
    {10, 256, 256, 16,  8, 212992},
    {12, 256, 319, 16, 10, 278528},
    {14, 256, 256, 16,  8, 360448},
    {16, 256, 256, 16,  8, 425984},
    {18, 257, 256, 17,  8, 491520},
    {20, 128, 283,  8,  9, 561152},
    {22,   3, 128,  1,  4, 598016},
  };
  for (int i = 0; i < 11; ++i) {
    int total = wspecs[i].nct * wspecs[i].nkt * 64;
    pack_w<<<dim3((total + 255) / 256), dim3(256), 0, stream>>>(
      (const float*)d_in[wspecs[i].idx], wp + wspecs[i].off,
      wspecs[i].OUT, wspecs[i].KIN, wspecs[i].nct, wspecs[i].nkt);
  }
  struct BSpec { int idx, OUT, OUTP, off; };
  const BSpec bspecs[11] = {
    { 3, 256, 256,    0}, { 5, 256, 256,  256}, { 7, 256, 256,  512}, { 9, 256, 256,  768},
    {11, 256, 256, 1024}, {13, 256, 256, 1280}, {15, 256, 256, 1536}, {17, 256, 256, 1792},
    {19, 257, 272, 2048}, {21, 128, 128, 2320}, {23,   3,  16, 2448},
  };
  for (int i = 0; i < 11; ++i) {
    pack_b<<<dim3((bspecs[i].OUTP + 255) / 256), dim3(256), 0, stream>>>(
      (const float*)d_in[bspecs[i].idx], bp + bspecs[i].off, bspecs[i].OUT, bspecs[i].OUTP);
  }

  hipFuncSetAttribute(reinterpret_cast<const void*>(nerf_fused),
                      hipFuncAttributeMaxDynamicSharedMemorySize, LDS_BYTES);
  nerf_fused<<<dim3(NPTS / ROWS), dim3(512), LDS_BYTES, stream>>>(xyz, dvec, wp, bp, (float*)d_out);
}